// Round 16
// baseline (228.272 us; speedup 1.0000x reference)
//
#include <hip/hip_runtime.h>

#define D 128
typedef unsigned short ushort_t;
typedef __attribute__((ext_vector_type(8))) short bf16x8;
typedef __attribute__((ext_vector_type(4))) float f32x4;

// ---------------- helpers ----------------
__device__ __forceinline__ float wred_max(float v){
#pragma unroll
  for (int o = 1; o < 64; o <<= 1) v = fmaxf(v, __shfl_xor(v, o, 64));
  return v;
}
__device__ __forceinline__ float wred_sum(float v){
#pragma unroll
  for (int o = 1; o < 64; o <<= 1) v += __shfl_xor(v, o, 64);
  return v;
}
__device__ __forceinline__ unsigned short f2bf(float f){
  unsigned u = __float_as_uint(f);
  unsigned r = (u + 0x7FFFu + ((u >> 16) & 1u)) >> 16;   // RNE
  return (unsigned short)r;
}
__device__ __forceinline__ float bflo(unsigned u){ return __uint_as_float(u << 16); }
__device__ __forceinline__ float bfhi(unsigned u){ return __uint_as_float(u & 0xFFFF0000u); }

// ---------------- init: pack 3 W's (hi bf16, B-frag layout) + zero cnt ----------------
// B frag 16x16x32: lane l holds B[k][c], c = ct*16+(l&15), k = s*32+(l>>4)*8+e.
__global__ __launch_bounds__(256) void k_init(const float* __restrict__ W0,
                                              const float* __restrict__ W1,
                                              const float* __restrict__ W2,
                                              ushort_t* __restrict__ Wp,
                                              int* __restrict__ cnt, int n){
  int b = blockIdx.x;
  if (b < 192){
    int wi = b >> 6;
    const float* W = wi == 0 ? W0 : (wi == 1 ? W1 : W2);
    ushort_t* dst = Wp + wi * 16384;
    int idx = (b & 63) * 256 + threadIdx.x;     // 0..16383
    int k = idx >> 7, c = idx & 127;
    int ct = c >> 4, s = k >> 5, lane = (c & 15) | (((k >> 3) & 3) << 4), e = k & 7;
    dst[((ct * 4 + s) * 64 + lane) * 8 + e] = f2bf(W[idx]);
  } else {
    int i = (b - 192) * 256 + threadIdx.x;
    if (i < n) cnt[i] = 0;
  }
}

// ---------------- MFMA GEMM body ----------------
// XF32: x split into hi+lo bf16, compute x_hi*W + x_lo*W (64 mfma); else bf16 in (32 mfma)
// A-matrix loads are NON-TEMPORAL (read-once stream; keep L2 for csr/cnt + gather rows)
template<bool XF32>
__device__ __forceinline__ void gemm_body(int bid, const void* __restrict__ Av,
                                          const ushort_t* __restrict__ Wp,
                                          const float* __restrict__ a_src,
                                          const float* __restrict__ a_dst,
                                          ushort_t* __restrict__ Hbf,
                                          float* __restrict__ as_,
                                          float* __restrict__ ad_,
                                          int n){
  int tid = threadIdx.x;
  int wid = tid >> 6, l = tid & 63;
  int kg = l >> 4, cin = l & 15;
  int r0 = bid * 64 + wid * 16;
  int row_l = r0 + cin;
  if (row_l > n - 1) row_l = n - 1;

  bf16x8 ah[4], al[4];
  if (XF32){
    const float* xp = (const float*)Av + (size_t)row_l * D + kg * 8;
#pragma unroll
    for (int s = 0; s < 4; s++){
      f32x4 f0 = __builtin_nontemporal_load((const f32x4*)(xp + s * 32));
      f32x4 f1 = __builtin_nontemporal_load((const f32x4*)(xp + s * 32 + 4));
      float fv[8] = {f0.x, f0.y, f0.z, f0.w, f1.x, f1.y, f1.z, f1.w};
#pragma unroll
      for (int e = 0; e < 8; e++){
        unsigned short h = f2bf(fv[e]);
        ah[s][e] = (short)h;
        float r = fv[e] - __uint_as_float((unsigned)h << 16);
        al[s][e] = (short)f2bf(r);
      }
    }
  } else {
    const ushort_t* xp = (const ushort_t*)Av + (size_t)row_l * D + kg * 8;
#pragma unroll
    for (int s = 0; s < 4; s++)
      ah[s] = __builtin_nontemporal_load((const bf16x8*)(xp + s * 32));
  }

  const bf16x8* Bh = (const bf16x8*)Wp;

  f32x4 acc[8];
#pragma unroll
  for (int ct = 0; ct < 8; ct++) acc[ct] = (f32x4){0.f, 0.f, 0.f, 0.f};

#pragma unroll
  for (int ct = 0; ct < 8; ct++)
#pragma unroll
    for (int s = 0; s < 4; s++){
      bf16x8 bh = Bh[(ct * 4 + s) * 64 + l];
      acc[ct] = __builtin_amdgcn_mfma_f32_16x16x32_bf16(ah[s], bh, acc[ct], 0, 0, 0);
      if (XF32)
        acc[ct] = __builtin_amdgcn_mfma_f32_16x16x32_bf16(al[s], bh, acc[ct], 0, 0, 0);
    }

  float asv[8], adv[8];
#pragma unroll
  for (int ct = 0; ct < 8; ct++){
    asv[ct] = a_src[ct * 16 + cin];
    adv[ct] = a_dst[ct * 16 + cin];
  }
#pragma unroll
  for (int j = 0; j < 4; j++){
    float ps = 0.f, pd = 0.f;
#pragma unroll
    for (int ct = 0; ct < 8; ct++){ ps += acc[ct][j] * asv[ct]; pd += acc[ct][j] * adv[ct]; }
#pragma unroll
    for (int o = 1; o < 16; o <<= 1){ ps += __shfl_xor(ps, o, 64); pd += __shfl_xor(pd, o, 64); }
    int row = r0 + kg * 4 + j;
    if (row < n){
      if (cin == 0) as_[row] = ps;
      if (cin == 1) ad_[row] = pd;
#pragma unroll
      for (int ct = 0; ct < 8; ct++)
        Hbf[(size_t)row * D + ct * 16 + cin] = f2bf(acc[ct][j]);
    }
  }
}

// layer-2/3 GEMM
__global__ __launch_bounds__(256) void k_gemm_mfma_bf(const void* __restrict__ Av,
                                                      const ushort_t* __restrict__ Wp,
                                                      const float* __restrict__ a_src,
                                                      const float* __restrict__ a_dst,
                                                      ushort_t* __restrict__ Hbf,
                                                      float* __restrict__ as_,
                                                      float* __restrict__ ad_,
                                                      int n){
  gemm_body<false>(blockIdx.x, Av, Wp, a_src, a_dst, Hbf, as_, ad_, n);
}

// fused: blocks [0, gemm_grid) = layer-1 GEMM; rest = XCD-sliced padded-CSR fill.
// Fill: chunk = f>>3 covers edges [chunk*1024, +1024); slice = blockIdx&7 owns dst
// range [slice*sliceN, +sliceN). Edge reads are NON-TEMPORAL: the 41MB edge
// re-read stream must not evict the slice's ~825KB cnt/csr working set from L2
// (that eviction is the source of the 5.3x csr write amplification).
__global__ __launch_bounds__(256) void k_gemm1_fill(const float* __restrict__ x,
                                                    const ushort_t* __restrict__ Wp,
                                                    const float* __restrict__ a_src,
                                                    const float* __restrict__ a_dst,
                                                    ushort_t* __restrict__ Hbf,
                                                    float* __restrict__ as_,
                                                    float* __restrict__ ad_,
                                                    int n, int gemm_grid,
                                                    const int* __restrict__ src,
                                                    const int* __restrict__ dst,
                                                    int E, int sliceN,
                                                    int* __restrict__ cnt,
                                                    ushort_t* __restrict__ csr_pad){
  int b = blockIdx.x;
  if (b < gemm_grid){
    gemm_body<true>(b, x, Wp, a_src, a_dst, Hbf, as_, ad_, n);
  } else {
    int f = b - gemm_grid;
    int chunk = f >> 3;
    int slice = b & 7;                        // XCD-affinity heuristic
    int d_lo = slice * sliceN;
    int d_hi = d_lo + sliceN;
    int e0 = chunk * 1024 + (int)threadIdx.x;
#pragma unroll
    for (int i = 0; i < 4; i++){
      int e = e0 + i * 256;
      if (e < E){
        int d = __builtin_nontemporal_load(&dst[e]);
        if (d >= d_lo && d < d_hi){
          int s = __builtin_nontemporal_load(&src[e]);
          int slot = atomicAdd(&cnt[d], 1);
          if (slot < 63) csr_pad[((size_t)d << 6) + slot] = (ushort_t)s;
        }
      }
    }
  }
}

// ---------------- aggregation: one wave per node, implicit self-loop, quad uint4 gather ----------------
template<bool OUTBF>
__global__ __launch_bounds__(256) void k_agg(const uint4* __restrict__ hb4,   // 16 uint4 per row
                                             const ushort_t* __restrict__ csr_pad,
                                             const int* __restrict__ cnt,
                                             const float* __restrict__ asrc,
                                             const float* __restrict__ adst,
                                             const float* __restrict__ bias,
                                             ushort_t* __restrict__ outb,
                                             float* __restrict__ outf,
                                             int relu, int n){
  int node = (blockIdx.x * 256 + threadIdx.x) >> 6;
  if (node >= n) return;
  int lane = threadIdx.x & 63;
  int q = lane & 15, g = lane >> 4;
  int degr = cnt[node]; if (degr > 63) degr = 63;
  int degp = degr + 1;                         // + implicit self loop at slot degr
  const ushort_t* eb = csr_pad + ((size_t)node << 6);
  float adn = adst[node];

  int s = node; float logit = -1e30f;
  if (lane < degr) s = eb[lane];
  if (lane <= degr){
    float xx = asrc[s] + adn;
    logit = xx >= 0.f ? xx : 0.2f * xx;
  }
  float m = wred_max(logit);
  float p = (lane <= degr) ? __expf(logit - m) : 0.f;
  float denom = wred_sum(p);
  float inv = 1.f / (denom + 1e-16f);

  float acc[8] = {0.f, 0.f, 0.f, 0.f, 0.f, 0.f, 0.f, 0.f};
#pragma unroll 2
  for (int j = 0; j < degp; j += 4){
    int slot = j + g;                          // j <= 60 -> slot <= 63
    int   sj = __shfl(s, slot, 64);
    float wj = (slot < degp) ? __shfl(p, slot, 64) : 0.f;
    uint4 v = hb4[(size_t)sj * 16 + q];
    acc[0] += wj * bflo(v.x); acc[1] += wj * bfhi(v.x);
    acc[2] += wj * bflo(v.y); acc[3] += wj * bfhi(v.y);
    acc[4] += wj * bflo(v.z); acc[5] += wj * bfhi(v.z);
    acc[6] += wj * bflo(v.w); acc[7] += wj * bfhi(v.w);
  }
#pragma unroll
  for (int o = 16; o < 64; o <<= 1){
#pragma unroll
    for (int i = 0; i < 8; i++) acc[i] += __shfl_xor(acc[i], o, 64);
  }

  if (g == 0){
    float4 b0 = *(const float4*)&bias[q * 8];
    float4 b1 = *(const float4*)&bias[q * 8 + 4];
    float o0 = acc[0] * inv + b0.x, o1 = acc[1] * inv + b0.y;
    float o2 = acc[2] * inv + b0.z, o3 = acc[3] * inv + b0.w;
    float o4 = acc[4] * inv + b1.x, o5 = acc[5] * inv + b1.y;
    float o6 = acc[6] * inv + b1.z, o7 = acc[7] * inv + b1.w;
    if (relu){
      o0 = fmaxf(o0, 0.f); o1 = fmaxf(o1, 0.f); o2 = fmaxf(o2, 0.f); o3 = fmaxf(o3, 0.f);
      o4 = fmaxf(o4, 0.f); o5 = fmaxf(o5, 0.f); o6 = fmaxf(o6, 0.f); o7 = fmaxf(o7, 0.f);
    }
    if (OUTBF){
      ushort4 u0, u1;
      u0.x = f2bf(o0); u0.y = f2bf(o1); u0.z = f2bf(o2); u0.w = f2bf(o3);
      u1.x = f2bf(o4); u1.y = f2bf(o5); u1.z = f2bf(o6); u1.w = f2bf(o7);
      *(ushort4*)&outb[(size_t)node * D + q * 8]     = u0;
      *(ushort4*)&outb[(size_t)node * D + q * 8 + 4] = u1;
    } else {
      *(float4*)&outf[(size_t)node * D + q * 8]     = make_float4(o0, o1, o2, o3);
      *(float4*)&outf[(size_t)node * D + q * 8 + 4] = make_float4(o4, o5, o6, o7);
    }
  }
}

// ---------------- fused pool + final linear ----------------
__device__ __forceinline__ int lbound(const int* a, int n, int key){
  int lo = 0, hi = n;
  while (lo < hi){ int mid = (lo + hi) >> 1; if (a[mid] < key) lo = mid + 1; else hi = mid; }
  return lo;
}

__global__ __launch_bounds__(128) void k_pool_final(const float* __restrict__ x,
                                                    const int* __restrict__ batch,
                                                    const float* __restrict__ Wl,
                                                    const float* __restrict__ bl,
                                                    float* __restrict__ out, int n){
  __shared__ float pl[128];
  int g = blockIdx.x;
  int c = threadIdx.x;
  int lo = lbound(batch, n, g);
  int hi = lbound(batch, n, g + 1);
  float sum = 0.f;
  for (int i = lo; i < hi; i++) sum += x[(size_t)i * D + c];
  float cnt = (float)(hi - lo);
  pl[c] = sum / fmaxf(cnt, 1.f);
  __syncthreads();
  float acc = bl[c];
#pragma unroll 4
  for (int k = 0; k < 128; k++) acc += pl[k] * Wl[(size_t)k * D + c];
  out[(size_t)g * D + c] = acc;
}

// ---------------- launch ----------------
extern "C" void kernel_launch(void* const* d_in, const int* in_sizes, int n_in,
                              void* d_out, int out_size, void* d_ws, size_t ws_size,
                              hipStream_t stream){
  const float* x     = (const float*)d_in[0];
  const int*   ei    = (const int*)d_in[1];
  const int*   batch = (const int*)d_in[3];
  const float* gW[3]  = {(const float*)d_in[4],  (const float*)d_in[8],  (const float*)d_in[12]};
  const float* gAs[3] = {(const float*)d_in[5],  (const float*)d_in[9],  (const float*)d_in[13]};
  const float* gAd[3] = {(const float*)d_in[6],  (const float*)d_in[10], (const float*)d_in[14]};
  const float* gB[3]  = {(const float*)d_in[7],  (const float*)d_in[11], (const float*)d_in[15]};
  const float* linW = (const float*)d_in[16];
  const float* linB = (const float*)d_in[17];
  float* outp = (float*)d_out;

  int N  = in_sizes[3];
  int E  = in_sizes[1] / 2;
  int G  = out_size / D;

  char* ws = (char*)d_ws;
  size_t off = 0;
  auto alloc = [&](size_t bytes)->void*{
    void* p = ws + off;
    off += (bytes + 255) & ~(size_t)255;
    return p;
  };
  float*    bufF    = (float*)alloc((size_t)N * D * 4);      // layer-3 agg out (fp32)
  ushort_t* bufB    = (ushort_t*)alloc((size_t)N * D * 2);   // layer-1/2 agg out (bf16)
  ushort_t* Hbf     = (ushort_t*)alloc((size_t)N * D * 2);   // h (bf16)
  float*    as_     = (float*)alloc((size_t)N * 4);
  float*    ad_     = (float*)alloc((size_t)N * 4);
  int*      cnt     = (int*)  alloc((size_t)N * 4);
  ushort_t* csr_pad = (ushort_t*)alloc((size_t)N * 64 * 2);  // padded CSR, K=64
  ushort_t* Wp      = (ushort_t*)alloc(3 * 16384 * 2);       // 3 packed W (hi only)
  (void)ws_size; (void)n_in;

  const int* esrc = ei;
  const int* edst = ei + E;

  int tpb = 256;
  int ngrid = (N + tpb - 1) / tpb;
  int gemm_grid = (N + 63) / 64;
  int node_grid = (N + 3) / 4;
  int nchunk = (E + 1023) / 1024;
  int sliceN = (N + 7) / 8;

  k_init<<<192 + ngrid, tpb, 0, stream>>>(gW[0], gW[1], gW[2], Wp, cnt, N);

  const uint4* hbu = (const uint4*)Hbf;

  // layer 1 GEMM (fp32 in, x hi+lo) fused with XCD-sliced CSR fill
  k_gemm1_fill<<<gemm_grid + nchunk * 8, tpb, 0, stream>>>(x, Wp, gAs[0], gAd[0], Hbf, as_, ad_, N,
                                                           gemm_grid, esrc, edst, E, sliceN, cnt, csr_pad);
  k_agg<true>  <<<node_grid, tpb, 0, stream>>>(hbu, csr_pad, cnt, as_, ad_, gB[0], bufB, nullptr, 1, N);
  // layer 2
  k_gemm_mfma_bf<<<gemm_grid, tpb, 0, stream>>>(bufB, Wp + 16384, gAs[1], gAd[1], Hbf, as_, ad_, N);
  k_agg<true>  <<<node_grid, tpb, 0, stream>>>(hbu, csr_pad, cnt, as_, ad_, gB[1], bufB, nullptr, 1, N);
  // layer 3
  k_gemm_mfma_bf<<<gemm_grid, tpb, 0, stream>>>(bufB, Wp + 32768, gAs[2], gAd[2], Hbf, as_, ad_, N);
  k_agg<false> <<<node_grid, tpb, 0, stream>>>(hbu, csr_pad, cnt, as_, ad_, gB[2], nullptr, bufF, 0, N);

  // fused pool + final linear
  k_pool_final<<<G, 128, 0, stream>>>(bufF, batch, linW, linB, outp, N);
}

// Round 17
// 206.983 us; speedup vs baseline: 1.1029x; 1.1029x over previous
//
#include <hip/hip_runtime.h>

#define D 128
typedef unsigned short ushort_t;
typedef __attribute__((ext_vector_type(8))) short bf16x8;
typedef __attribute__((ext_vector_type(4))) float f32x4;

// ---------------- helpers ----------------
__device__ __forceinline__ float wred_max(float v){
#pragma unroll
  for (int o = 1; o < 64; o <<= 1) v = fmaxf(v, __shfl_xor(v, o, 64));
  return v;
}
__device__ __forceinline__ float wred_sum(float v){
#pragma unroll
  for (int o = 1; o < 64; o <<= 1) v += __shfl_xor(v, o, 64);
  return v;
}
__device__ __forceinline__ unsigned short f2bf(float f){
  unsigned u = __float_as_uint(f);
  unsigned r = (u + 0x7FFFu + ((u >> 16) & 1u)) >> 16;   // RNE
  return (unsigned short)r;
}
__device__ __forceinline__ float bflo(unsigned u){ return __uint_as_float(u << 16); }
__device__ __forceinline__ float bfhi(unsigned u){ return __uint_as_float(u & 0xFFFF0000u); }

// ---------------- init: pack 3 W's (hi bf16, B-frag layout) + zero cnt ----------------
// B frag 16x16x32: lane l holds B[k][c], c = ct*16+(l&15), k = s*32+(l>>4)*8+e.
__global__ __launch_bounds__(256) void k_init(const float* __restrict__ W0,
                                              const float* __restrict__ W1,
                                              const float* __restrict__ W2,
                                              ushort_t* __restrict__ Wp,
                                              int* __restrict__ cnt, int n){
  int b = blockIdx.x;
  if (b < 192){
    int wi = b >> 6;
    const float* W = wi == 0 ? W0 : (wi == 1 ? W1 : W2);
    ushort_t* dst = Wp + wi * 16384;
    int idx = (b & 63) * 256 + threadIdx.x;     // 0..16383
    int k = idx >> 7, c = idx & 127;
    int ct = c >> 4, s = k >> 5, lane = (c & 15) | (((k >> 3) & 3) << 4), e = k & 7;
    dst[((ct * 4 + s) * 64 + lane) * 8 + e] = f2bf(W[idx]);
  } else {
    int i = (b - 192) * 256 + threadIdx.x;
    if (i < n) cnt[i] = 0;
  }
}

// ---------------- MFMA GEMM body ----------------
// XF32: x split into hi+lo bf16, compute x_hi*W + x_lo*W (64 mfma); else bf16 in (32 mfma)
template<bool XF32>
__device__ __forceinline__ void gemm_body(int bid, const void* __restrict__ Av,
                                          const ushort_t* __restrict__ Wp,
                                          const float* __restrict__ a_src,
                                          const float* __restrict__ a_dst,
                                          ushort_t* __restrict__ Hbf,
                                          float* __restrict__ as_,
                                          float* __restrict__ ad_,
                                          int n){
  int tid = threadIdx.x;
  int wid = tid >> 6, l = tid & 63;
  int kg = l >> 4, cin = l & 15;
  int r0 = bid * 64 + wid * 16;
  int row_l = r0 + cin;
  if (row_l > n - 1) row_l = n - 1;

  bf16x8 ah[4], al[4];
  if (XF32){
    const float* xp = (const float*)Av + (size_t)row_l * D + kg * 8;
#pragma unroll
    for (int s = 0; s < 4; s++){
      float4 f0 = *(const float4*)(xp + s * 32);
      float4 f1 = *(const float4*)(xp + s * 32 + 4);
      float fv[8] = {f0.x, f0.y, f0.z, f0.w, f1.x, f1.y, f1.z, f1.w};
#pragma unroll
      for (int e = 0; e < 8; e++){
        unsigned short h = f2bf(fv[e]);
        ah[s][e] = (short)h;
        float r = fv[e] - __uint_as_float((unsigned)h << 16);
        al[s][e] = (short)f2bf(r);
      }
    }
  } else {
    const ushort_t* xp = (const ushort_t*)Av + (size_t)row_l * D + kg * 8;
#pragma unroll
    for (int s = 0; s < 4; s++) ah[s] = *(const bf16x8*)(xp + s * 32);
  }

  const bf16x8* Bh = (const bf16x8*)Wp;

  f32x4 acc[8];
#pragma unroll
  for (int ct = 0; ct < 8; ct++) acc[ct] = (f32x4){0.f, 0.f, 0.f, 0.f};

#pragma unroll
  for (int ct = 0; ct < 8; ct++)
#pragma unroll
    for (int s = 0; s < 4; s++){
      bf16x8 bh = Bh[(ct * 4 + s) * 64 + l];
      acc[ct] = __builtin_amdgcn_mfma_f32_16x16x32_bf16(ah[s], bh, acc[ct], 0, 0, 0);
      if (XF32)
        acc[ct] = __builtin_amdgcn_mfma_f32_16x16x32_bf16(al[s], bh, acc[ct], 0, 0, 0);
    }

  float asv[8], adv[8];
#pragma unroll
  for (int ct = 0; ct < 8; ct++){
    asv[ct] = a_src[ct * 16 + cin];
    adv[ct] = a_dst[ct * 16 + cin];
  }
#pragma unroll
  for (int j = 0; j < 4; j++){
    float ps = 0.f, pd = 0.f;
#pragma unroll
    for (int ct = 0; ct < 8; ct++){ ps += acc[ct][j] * asv[ct]; pd += acc[ct][j] * adv[ct]; }
#pragma unroll
    for (int o = 1; o < 16; o <<= 1){ ps += __shfl_xor(ps, o, 64); pd += __shfl_xor(pd, o, 64); }
    int row = r0 + kg * 4 + j;
    if (row < n){
      if (cin == 0) as_[row] = ps;
      if (cin == 1) ad_[row] = pd;
#pragma unroll
      for (int ct = 0; ct < 8; ct++)
        Hbf[(size_t)row * D + ct * 16 + cin] = f2bf(acc[ct][j]);
    }
  }
}

// layer-2/3 GEMM
__global__ __launch_bounds__(256) void k_gemm_mfma_bf(const void* __restrict__ Av,
                                                      const ushort_t* __restrict__ Wp,
                                                      const float* __restrict__ a_src,
                                                      const float* __restrict__ a_dst,
                                                      ushort_t* __restrict__ Hbf,
                                                      float* __restrict__ as_,
                                                      float* __restrict__ ad_,
                                                      int n){
  gemm_body<false>(blockIdx.x, Av, Wp, a_src, a_dst, Hbf, as_, ad_, n);
}

// fused: blocks [0, gemm_grid) = layer-1 GEMM; rest = XCD-sliced padded-CSR fill.
// Fill: chunk = f>>3 covers edges [chunk*1024, +1024); slice = blockIdx&7 owns dst
// range [slice*sliceN, +sliceN) -> all writes to a given cnt/csr line come from one
// XCD. Chunk=1024 (4 serial iters/thread) keeps wave-level TLP high on the
// dependent atomicAdd->store chain.
__global__ __launch_bounds__(256) void k_gemm1_fill(const float* __restrict__ x,
                                                    const ushort_t* __restrict__ Wp,
                                                    const float* __restrict__ a_src,
                                                    const float* __restrict__ a_dst,
                                                    ushort_t* __restrict__ Hbf,
                                                    float* __restrict__ as_,
                                                    float* __restrict__ ad_,
                                                    int n, int gemm_grid,
                                                    const int* __restrict__ src,
                                                    const int* __restrict__ dst,
                                                    int E, int sliceN,
                                                    int* __restrict__ cnt,
                                                    ushort_t* __restrict__ csr_pad){
  int b = blockIdx.x;
  if (b < gemm_grid){
    gemm_body<true>(b, x, Wp, a_src, a_dst, Hbf, as_, ad_, n);
  } else {
    int f = b - gemm_grid;
    int chunk = f >> 3;
    int slice = b & 7;                        // XCD-affinity heuristic
    int d_lo = slice * sliceN;
    int d_hi = d_lo + sliceN;
    int e0 = chunk * 1024 + (int)threadIdx.x;
#pragma unroll
    for (int i = 0; i < 4; i++){
      int e = e0 + i * 256;
      if (e < E){
        int d = dst[e];
        if (d >= d_lo && d < d_hi){
          int s = src[e];
          int slot = atomicAdd(&cnt[d], 1);
          if (slot < 63) csr_pad[((size_t)d << 6) + slot] = (ushort_t)s;
        }
      }
    }
  }
}

// ---------------- aggregation: one wave per node, implicit self-loop, quad uint4 gather ----------------
template<bool OUTBF>
__global__ __launch_bounds__(256) void k_agg(const uint4* __restrict__ hb4,   // 16 uint4 per row
                                             const ushort_t* __restrict__ csr_pad,
                                             const int* __restrict__ cnt,
                                             const float* __restrict__ asrc,
                                             const float* __restrict__ adst,
                                             const float* __restrict__ bias,
                                             ushort_t* __restrict__ outb,
                                             float* __restrict__ outf,
                                             int relu, int n){
  int node = (blockIdx.x * 256 + threadIdx.x) >> 6;
  if (node >= n) return;
  int lane = threadIdx.x & 63;
  int q = lane & 15, g = lane >> 4;
  int degr = cnt[node]; if (degr > 63) degr = 63;
  int degp = degr + 1;                         // + implicit self loop at slot degr
  const ushort_t* eb = csr_pad + ((size_t)node << 6);
  float adn = adst[node];

  int s = node; float logit = -1e30f;
  if (lane < degr) s = eb[lane];
  if (lane <= degr){
    float xx = asrc[s] + adn;
    logit = xx >= 0.f ? xx : 0.2f * xx;
  }
  float m = wred_max(logit);
  float p = (lane <= degr) ? __expf(logit - m) : 0.f;
  float denom = wred_sum(p);
  float inv = 1.f / (denom + 1e-16f);

  float acc[8] = {0.f, 0.f, 0.f, 0.f, 0.f, 0.f, 0.f, 0.f};
#pragma unroll 2
  for (int j = 0; j < degp; j += 4){
    int slot = j + g;                          // j <= 60 -> slot <= 63
    int   sj = __shfl(s, slot, 64);
    float wj = (slot < degp) ? __shfl(p, slot, 64) : 0.f;
    uint4 v = hb4[(size_t)sj * 16 + q];
    acc[0] += wj * bflo(v.x); acc[1] += wj * bfhi(v.x);
    acc[2] += wj * bflo(v.y); acc[3] += wj * bfhi(v.y);
    acc[4] += wj * bflo(v.z); acc[5] += wj * bfhi(v.z);
    acc[6] += wj * bflo(v.w); acc[7] += wj * bfhi(v.w);
  }
#pragma unroll
  for (int o = 16; o < 64; o <<= 1){
#pragma unroll
    for (int i = 0; i < 8; i++) acc[i] += __shfl_xor(acc[i], o, 64);
  }

  if (g == 0){
    float4 b0 = *(const float4*)&bias[q * 8];
    float4 b1 = *(const float4*)&bias[q * 8 + 4];
    float o0 = acc[0] * inv + b0.x, o1 = acc[1] * inv + b0.y;
    float o2 = acc[2] * inv + b0.z, o3 = acc[3] * inv + b0.w;
    float o4 = acc[4] * inv + b1.x, o5 = acc[5] * inv + b1.y;
    float o6 = acc[6] * inv + b1.z, o7 = acc[7] * inv + b1.w;
    if (relu){
      o0 = fmaxf(o0, 0.f); o1 = fmaxf(o1, 0.f); o2 = fmaxf(o2, 0.f); o3 = fmaxf(o3, 0.f);
      o4 = fmaxf(o4, 0.f); o5 = fmaxf(o5, 0.f); o6 = fmaxf(o6, 0.f); o7 = fmaxf(o7, 0.f);
    }
    if (OUTBF){
      ushort4 u0, u1;
      u0.x = f2bf(o0); u0.y = f2bf(o1); u0.z = f2bf(o2); u0.w = f2bf(o3);
      u1.x = f2bf(o4); u1.y = f2bf(o5); u1.z = f2bf(o6); u1.w = f2bf(o7);
      *(ushort4*)&outb[(size_t)node * D + q * 8]     = u0;
      *(ushort4*)&outb[(size_t)node * D + q * 8 + 4] = u1;
    } else {
      *(float4*)&outf[(size_t)node * D + q * 8]     = make_float4(o0, o1, o2, o3);
      *(float4*)&outf[(size_t)node * D + q * 8 + 4] = make_float4(o4, o5, o6, o7);
    }
  }
}

// ---------------- fused pool + final linear ----------------
__device__ __forceinline__ int lbound(const int* a, int n, int key){
  int lo = 0, hi = n;
  while (lo < hi){ int mid = (lo + hi) >> 1; if (a[mid] < key) lo = mid + 1; else hi = mid; }
  return lo;
}

__global__ __launch_bounds__(128) void k_pool_final(const float* __restrict__ x,
                                                    const int* __restrict__ batch,
                                                    const float* __restrict__ Wl,
                                                    const float* __restrict__ bl,
                                                    float* __restrict__ out, int n){
  __shared__ float pl[128];
  int g = blockIdx.x;
  int c = threadIdx.x;
  int lo = lbound(batch, n, g);
  int hi = lbound(batch, n, g + 1);
  float sum = 0.f;
  for (int i = lo; i < hi; i++) sum += x[(size_t)i * D + c];
  float cnt = (float)(hi - lo);
  pl[c] = sum / fmaxf(cnt, 1.f);
  __syncthreads();
  float acc = bl[c];
#pragma unroll 4
  for (int k = 0; k < 128; k++) acc += pl[k] * Wl[(size_t)k * D + c];
  out[(size_t)g * D + c] = acc;
}

// ---------------- launch ----------------
extern "C" void kernel_launch(void* const* d_in, const int* in_sizes, int n_in,
                              void* d_out, int out_size, void* d_ws, size_t ws_size,
                              hipStream_t stream){
  const float* x     = (const float*)d_in[0];
  const int*   ei    = (const int*)d_in[1];
  const int*   batch = (const int*)d_in[3];
  const float* gW[3]  = {(const float*)d_in[4],  (const float*)d_in[8],  (const float*)d_in[12]};
  const float* gAs[3] = {(const float*)d_in[5],  (const float*)d_in[9],  (const float*)d_in[13]};
  const float* gAd[3] = {(const float*)d_in[6],  (const float*)d_in[10], (const float*)d_in[14]};
  const float* gB[3]  = {(const float*)d_in[7],  (const float*)d_in[11], (const float*)d_in[15]};
  const float* linW = (const float*)d_in[16];
  const float* linB = (const float*)d_in[17];
  float* outp = (float*)d_out;

  int N  = in_sizes[3];
  int E  = in_sizes[1] / 2;
  int G  = out_size / D;

  char* ws = (char*)d_ws;
  size_t off = 0;
  auto alloc = [&](size_t bytes)->void*{
    void* p = ws + off;
    off += (bytes + 255) & ~(size_t)255;
    return p;
  };
  float*    bufF    = (float*)alloc((size_t)N * D * 4);      // layer-3 agg out (fp32)
  ushort_t* bufB    = (ushort_t*)alloc((size_t)N * D * 2);   // layer-1/2 agg out (bf16)
  ushort_t* Hbf     = (ushort_t*)alloc((size_t)N * D * 2);   // h (bf16)
  float*    as_     = (float*)alloc((size_t)N * 4);
  float*    ad_     = (float*)alloc((size_t)N * 4);
  int*      cnt     = (int*)  alloc((size_t)N * 4);
  ushort_t* csr_pad = (ushort_t*)alloc((size_t)N * 64 * 2);  // padded CSR, K=64
  ushort_t* Wp      = (ushort_t*)alloc(3 * 16384 * 2);       // 3 packed W (hi only)
  (void)ws_size; (void)n_in;

  const int* esrc = ei;
  const int* edst = ei + E;

  int tpb = 256;
  int ngrid = (N + tpb - 1) / tpb;
  int gemm_grid = (N + 63) / 64;
  int node_grid = (N + 3) / 4;
  int nchunk = (E + 1023) / 1024;
  int sliceN = (N + 7) / 8;

  k_init<<<192 + ngrid, tpb, 0, stream>>>(gW[0], gW[1], gW[2], Wp, cnt, N);

  const uint4* hbu = (const uint4*)Hbf;

  // layer 1 GEMM (fp32 in, x hi+lo) fused with XCD-sliced CSR fill
  k_gemm1_fill<<<gemm_grid + nchunk * 8, tpb, 0, stream>>>(x, Wp, gAs[0], gAd[0], Hbf, as_, ad_, N,
                                                           gemm_grid, esrc, edst, E, sliceN, cnt, csr_pad);
  k_agg<true>  <<<node_grid, tpb, 0, stream>>>(hbu, csr_pad, cnt, as_, ad_, gB[0], bufB, nullptr, 1, N);
  // layer 2
  k_gemm_mfma_bf<<<gemm_grid, tpb, 0, stream>>>(bufB, Wp + 16384, gAs[1], gAd[1], Hbf, as_, ad_, N);
  k_agg<true>  <<<node_grid, tpb, 0, stream>>>(hbu, csr_pad, cnt, as_, ad_, gB[1], bufB, nullptr, 1, N);
  // layer 3
  k_gemm_mfma_bf<<<gemm_grid, tpb, 0, stream>>>(bufB, Wp + 32768, gAs[2], gAd[2], Hbf, as_, ad_, N);
  k_agg<false> <<<node_grid, tpb, 0, stream>>>(hbu, csr_pad, cnt, as_, ad_, gB[2], nullptr, bufF, 0, N);

  // fused pool + final linear
  k_pool_final<<<G, 128, 0, stream>>>(bufF, batch, linW, linB, outp, N);
}